// Round 2
// baseline (127.706 us; speedup 1.0000x reference)
//
#include <hip/hip_runtime.h>

// LengthRegulator: expanded[b,pos,:] = encoder_out[b, searchsorted(cum_dur[b], pos, 'right'), :]
// for pos < min(mel_len, max_len), else 0; mel_lens[b] = cum_dur[b, T-1].
//
// Shapes fixed by the reference: B=16, T=512, D=384; max_len derived from out_size.
// d_out layout: [B*max_len*D floats expanded][B floats mel_lens].
//
// v2b changes vs baseline (123.8us, kernel ~61us):
//  - scan: 18-barrier Hillis-Steele -> 3-barrier wave-shuffle scan
//    (6x __shfl_up per 64-lane wave + 8-elem cross-wave offset sum).
//  - output stores are nontemporal (96 MiB stream >> 32 MiB L2; keep L2
//    for the encoder_out gather reads, which have ~3.5x reuse).
//    NOTE: __builtin_nontemporal_store needs a NATIVE vector type, not
//    HIP's float4 class -> use ext_vector_type(4) float.
//  - blocks entirely past mel (avg ~56% of frames) take a barrier-free
//    pure-zero path (no token binary search).

#define LR_B       16
#define LR_T       512
#define LR_D4      96          // D/4 float4s per frame (D=384)
#define LR_FRAMES  64          // output frames per block
#define LR_THREADS 512
#define LR_WAVES   (LR_THREADS / 64)

typedef float f32x4 __attribute__((ext_vector_type(4)));

__global__ __launch_bounds__(LR_THREADS)
void lr_expand_kernel(const f32x4* __restrict__ enc,   // [B*T*D4] float4
                      const int*   __restrict__ dur,   // [B*T]
                      float*       __restrict__ out,   // [B*max_len*D + B]
                      int max_len) {
    const int b    = blockIdx.y;
    const int pos0 = blockIdx.x * LR_FRAMES;
    const int tid  = threadIdx.x;
    const int lane = tid & 63;
    const int wid  = tid >> 6;         // wave id, 0..7

    __shared__ int s_cum[LR_T];
    __shared__ int s_wsum[LR_WAVES];
    __shared__ int s_tok[LR_FRAMES];

    // ---- inclusive scan of the duration row: wave shuffles, 3 barriers ----
    int v = dur[b * LR_T + tid];
#pragma unroll
    for (int off = 1; off < 64; off <<= 1) {
        int n = __shfl_up(v, off, 64);
        if (lane >= off) v += n;
    }
    if (lane == 63) s_wsum[wid] = v;
    __syncthreads();
    int woff = 0;
#pragma unroll
    for (int w = 0; w < LR_WAVES; ++w)
        woff += (w < wid) ? s_wsum[w] : 0;   // 8-elem broadcast reads, redundant per thread (cheap)
    s_cum[tid] = v + woff;
    __syncthreads();

    const int mel_raw = s_cum[LR_T - 1];
    const int mel     = min(mel_raw, max_len);

    // mel_lens tail (written once per batch, by the chunk-0 block)
    if (blockIdx.x == 0 && tid == 0) {
        out[(size_t)LR_B * max_len * (LR_D4 * 4) + b] = (float)mel_raw;
    }

    f32x4* out4 = (f32x4*)out;
    const size_t out_base = ((size_t)b * max_len + pos0) * LR_D4;
    const f32x4 zero4 = {0.f, 0.f, 0.f, 0.f};

    // ---- fast path: block entirely past mel -> pure streaming zero-fill ----
    if (pos0 >= mel) {
#pragma unroll
        for (int it = 0; it < (LR_FRAMES * LR_D4) / LR_THREADS; ++it) {
            int j   = it * LR_THREADS + tid;
            int f   = j / LR_D4;
            int pos = pos0 + f;
            if (pos >= max_len) continue;   // guard for non-multiple max_len
            __builtin_nontemporal_store(zero4, &out4[out_base + j]);
        }
        return;  // whole block exits together (pos0, mel are block-uniform)
    }

    // ---- per-frame token index: upper_bound(cum, pos), clipped to T-1 ----
    if (tid < LR_FRAMES) {
        int pos = pos0 + tid;
        int lo = 0, hi = LR_T;
        while (lo < hi) {
            int mid = (lo + hi) >> 1;
            if (s_cum[mid] <= pos) lo = mid + 1; else hi = mid;
        }
        s_tok[tid] = min(lo, LR_T - 1);
    }
    __syncthreads();

    // ---- copy phase: LR_FRAMES frames x LR_D4 float4, coalesced, nt stores ----
#pragma unroll
    for (int it = 0; it < (LR_FRAMES * LR_D4) / LR_THREADS; ++it) {
        int j   = it * LR_THREADS + tid;
        int f   = j / LR_D4;
        int d4  = j - f * LR_D4;
        int pos = pos0 + f;
        if (pos >= max_len) continue;
        f32x4 val = zero4;
        if (pos < mel) {
            val = enc[(size_t)(b * LR_T + s_tok[f]) * LR_D4 + d4];
        }
        __builtin_nontemporal_store(val, &out4[out_base + j]);
    }
}

extern "C" void kernel_launch(void* const* d_in, const int* in_sizes, int n_in,
                              void* d_out, int out_size, void* d_ws, size_t ws_size,
                              hipStream_t stream) {
    const f32x4* enc = (const f32x4*)d_in[0];   // encoder_out f32 [B,T,D]
    const int*   dur = (const int*)d_in[1];     // durations i32 [B,T]
    float*       out = (float*)d_out;

    // out_size = B*max_len*D + B  ->  max_len
    const int max_len = (out_size - LR_B) / (LR_B * LR_D4 * 4);

    dim3 grid((max_len + LR_FRAMES - 1) / LR_FRAMES, LR_B);
    lr_expand_kernel<<<grid, LR_THREADS, 0, stream>>>(enc, dur, out, max_len);
}